// Round 14
// baseline (270.188 us; speedup 1.0000x reference)
//
#include <hip/hip_runtime.h>
#include <math.h>

// TGCN: bf16 feature-space GCN aggregation (fp32 accum) -> single fused GRU
// kernel (merged Z+R phase sharing A-reads, double-buffered B-frags; B-slice
// in REGISTERS per wave, A in LDS). CSR-by-dst with ZERO global atomics;
// interleaved int2 {src, w*dinv_s} payload (dinv_d applied in agg epilogue).

#define HD 128
#define RBITS 13
#define RSIZE 8192          // nodes per histogram/fill range

typedef __attribute__((ext_vector_type(8))) short short8;
typedef __attribute__((ext_vector_type(4))) float f32x4;

__device__ __forceinline__ ushort f2bf(float f) {
    union { float f; unsigned u; } v; v.f = f;
    unsigned r = (v.u + 0x7FFFu + ((v.u >> 16) & 1u)) >> 16;
    return (ushort)r;
}
__device__ __forceinline__ float bf2f(ushort h) {
    union { unsigned u; float f; } v; v.u = ((unsigned)h) << 16;
    return v.f;
}
__device__ __forceinline__ float bflo(unsigned u) {
    union { unsigned u; float f; } v; v.u = u << 16; return v.f;
}
__device__ __forceinline__ float bfhi(unsigned u) {
    union { unsigned u; float f; } v; v.u = u & 0xFFFF0000u; return v.f;
}
__device__ __forceinline__ float fast_sigmoid(float x) {
    return 1.0f / (1.0f + __expf(-x));
}
__device__ __forceinline__ float fast_tanh(float x) {
    float e = __expf(-2.0f * fabsf(x));
    float m = (1.0f - e) / (1.0f + e);
    return copysignf(m, x);
}

// nf -> bf16, h0 -> bf16 (vectorized)
__global__ void prep_kernel(const float* __restrict__ nf, const float* __restrict__ h0,
                            ushort* __restrict__ nfb, ushort* __restrict__ h0b, int n) {
    int idx = blockIdx.x * 256 + threadIdx.x;
    int total8 = n * (HD / 8);
    if (idx < total8) {
        const float4* p = (const float4*)(nf + (size_t)idx * 8);
        float4 x = p[0], y = p[1];
        short8 o;
        o[0] = (short)f2bf(x.x); o[1] = (short)f2bf(x.y);
        o[2] = (short)f2bf(x.z); o[3] = (short)f2bf(x.w);
        o[4] = (short)f2bf(y.x); o[5] = (short)f2bf(y.y);
        o[6] = (short)f2bf(y.z); o[7] = (short)f2bf(y.w);
        *(short8*)(nfb + (size_t)idx * 8) = o;
        const float4* q = (const float4*)(h0 + (size_t)idx * 8);
        float4 a = q[0], b = q[1];
        short8 o2;
        o2[0] = (short)f2bf(a.x); o2[1] = (short)f2bf(a.y);
        o2[2] = (short)f2bf(a.z); o2[3] = (short)f2bf(a.w);
        o2[4] = (short)f2bf(b.x); o2[5] = (short)f2bf(b.y);
        o2[6] = (short)f2bf(b.z); o2[7] = (short)f2bf(b.w);
        *(short8*)(h0b + (size_t)idx * 8) = o2;
    }
}

// LDS-privatized histogram. Block (r = bid%NR, c = bid/NR): counts/weights of
// dst in range r over edge chunk c. Flush = plain coalesced stores.
__global__ __launch_bounds__(256) void hist_lds_kernel(
        const int* __restrict__ dst, const float* __restrict__ w,
        int* __restrict__ pc, float* __restrict__ pw,
        int NPAD, int NR, int EC, int E) {
    __shared__ int lc[RSIZE];
    __shared__ float lw[RSIZE];
    int r = blockIdx.x % NR;
    int c = blockIdx.x / NR;
    int t = threadIdx.x;
    for (int b = t; b < RSIZE; b += 256) { lc[b] = 0; lw[b] = 0.0f; }
    __syncthreads();
    int base = c * EC;
    int end = min(base + EC, E);
    int rbase = r << RBITS;
    for (int e = base + t; e < end; e += 256) {
        int d = dst[e];
        float wv = w[e];
        if ((d >> RBITS) == r) {
            atomicAdd(&lc[d - rbase], 1);
            atomicAdd(&lw[d - rbase], wv);
        }
    }
    __syncthreads();
    size_t o = (size_t)c * NPAD + rbase;
    for (int b = t; b < RSIZE; b += 256) {
        pc[o + b] = lc[b];
        pw[o + b] = lw[b];
    }
}

// counts[i] = sum_c pc[c][i];  dinv[i] = rsqrt(1 + sum_c pw[c][i])
__global__ __launch_bounds__(256) void reduce_hist_kernel(
        const int* __restrict__ pc, const float* __restrict__ pw,
        int* __restrict__ counts, float* __restrict__ dinv,
        int NPAD, int NEC, int N) {
    int i = blockIdx.x * 256 + threadIdx.x;
    if (i >= N) return;
    int ctot = 0;
    float d = 1.0f;   // self-loop
    for (int c = 0; c < NEC; ++c) {
        ctot += pc[(size_t)c * NPAD + i];
        d += pw[(size_t)c * NPAD + i];
    }
    counts[i] = ctot;
    dinv[i] = (d > 0.0f) ? rsqrtf(d) : 0.0f;
}

// ---- hierarchical scan: partial sums (1024 elems / 256-thr block) ----
__global__ __launch_bounds__(256) void scan_partial_kernel(
        const int* __restrict__ counts, int* __restrict__ bsums, int n) {
    __shared__ int ws[4];
    int b = blockIdx.x, t = threadIdx.x;
    int idx = b * 1024 + t * 4;
    int4 v = {0, 0, 0, 0};
    if (idx + 3 < n) v = *(const int4*)(counts + idx);
    else {
        if (idx < n) v.x = counts[idx];
        if (idx + 1 < n) v.y = counts[idx + 1];
        if (idx + 2 < n) v.z = counts[idx + 2];
        if (idx + 3 < n) v.w = counts[idx + 3];
    }
    int s = v.x + v.y + v.z + v.w;
    for (int off = 1; off < 64; off <<= 1) s += __shfl_xor(s, off, 64);
    if ((t & 63) == 0) ws[t >> 6] = s;
    __syncthreads();
    if (t == 0) bsums[b] = ws[0] + ws[1] + ws[2] + ws[3];
}

// scan of nb (<=1024) block sums -> exclusive; writes row_ptr[n]
__global__ __launch_bounds__(1024) void scan_bsums_kernel(
        int* __restrict__ bsums, int* __restrict__ rp_total, int nb) {
    __shared__ int ws[16];
    int t = threadIdx.x;
    int v = (t < nb) ? bsums[t] : 0;
    int lane = t & 63, wid = t >> 6;
    int x = v;
    for (int off = 1; off < 64; off <<= 1) {
        int y = __shfl_up(x, off, 64);
        if (lane >= off) x += y;
    }
    if (lane == 63) ws[wid] = x;
    __syncthreads();
    if (wid == 0) {
        int s = (lane < 16) ? ws[lane] : 0;
        for (int off = 1; off < 16; off <<= 1) {
            int y = __shfl_up(s, off, 64);
            if (lane >= off) s += y;
        }
        if (lane < 16) ws[lane] = s;
    }
    __syncthreads();
    int excl = x - v + ((wid == 0) ? 0 : ws[wid - 1]);
    if (t < nb) bsums[t] = excl;
    if (t == nb - 1) *rp_total = excl + v;
}

// final: per-block local scan + block offset -> row_ptr
__global__ __launch_bounds__(256) void scan_final_kernel(
        const int* __restrict__ counts, const int* __restrict__ bsums,
        int* __restrict__ row_ptr, int n) {
    __shared__ int ws[4];
    int b = blockIdx.x, t = threadIdx.x;
    int idx = b * 1024 + t * 4;
    int4 v = {0, 0, 0, 0};
    if (idx + 3 < n) v = *(const int4*)(counts + idx);
    else {
        if (idx < n) v.x = counts[idx];
        if (idx + 1 < n) v.y = counts[idx + 1];
        if (idx + 2 < n) v.z = counts[idx + 2];
        if (idx + 3 < n) v.w = counts[idx + 3];
    }
    int s = v.x + v.y + v.z + v.w;
    int lane = t & 63, wid = t >> 6;
    int x = s;
    for (int off = 1; off < 64; off <<= 1) {
        int y = __shfl_up(x, off, 64);
        if (lane >= off) x += y;
    }
    if (lane == 63) ws[wid] = x;
    __syncthreads();
    int woff = 0;
    for (int wv = 0; wv < wid; ++wv) woff += ws[wv];
    int run = bsums[b] + woff + x - s;
    int4 rp;
    rp.x = run; rp.y = run + v.x; rp.z = rp.y + v.y; rp.w = rp.z + v.z;
    if (idx + 3 < n) {
        *(int4*)(row_ptr + idx) = rp;
    } else {
        if (idx < n) row_ptr[idx] = rp.x;
        if (idx + 1 < n) row_ptr[idx + 1] = rp.y;
        if (idx + 2 < n) row_ptr[idx + 2] = rp.z;
        if (idx + 3 < n) row_ptr[idx + 3] = rp.w;
    }
}

// pc[c][d] (counts) -> per-chunk CSR base offsets (in place)
__global__ __launch_bounds__(256) void col_scan_kernel(
        const int* __restrict__ row_ptr, int* __restrict__ pc,
        int NPAD, int NEC, int n) {
    int i = blockIdx.x * 256 + threadIdx.x;
    if (i >= n) return;
    int run = row_ptr[i];
    for (int c = 0; c < NEC; ++c) {
        size_t idx = (size_t)c * NPAD + i;
        int v = pc[idx];
        pc[idx] = run;
        run += v;
    }
}

// fill: block (c,r); pco range-slice preloaded into LDS; packed ushort ranks;
// ONE int2 {src, w*dinv_s} store per edge.
__global__ __launch_bounds__(512) void fill2d_kernel(
        const int* __restrict__ src, const int* __restrict__ dst,
        const float* __restrict__ w, const float* __restrict__ dinv,
        const int* __restrict__ pc, int2* __restrict__ es,
        int NPAD, int NR, int EC, int E) {
    __shared__ int po[RSIZE];            // 32KB preloaded base offsets
    __shared__ unsigned pk[RSIZE / 2];   // 16KB packed ushort cursors
    int r = blockIdx.x % NR;
    int c = blockIdx.x / NR;
    int t = threadIdx.x;
    const int* __restrict__ pco = pc + (size_t)c * NPAD + (r << RBITS);
    for (int b = t; b < RSIZE / 2; b += 512) pk[b] = 0u;
    for (int b = t; b < RSIZE; b += 512) po[b] = pco[b];
    __syncthreads();
    int base = c * EC;
    int end = min(base + EC, E);
    int rbase = r << RBITS;
    for (int e = base + t; e < end; e += 512) {
        int d = dst[e];
        if ((d >> RBITS) == r) {
            int dl = d - rbase;
            unsigned sh = (dl & 1) * 16;
            unsigned old = atomicAdd(&pk[dl >> 1], 1u << sh);
            int rank = (int)((old >> sh) & 0xFFFFu);
            int pos = po[dl] + rank;
            int s = src[e];
            float nv = dinv[s] * w[e];        // dinv[d] applied in agg epilogue
            int2 ev;
            ev.x = s;
            ev.y = __float_as_int(nv);
            es[pos] = ev;
        }
    }
}

// Fused-weight build, parallel+coalesced. grid (3,16), 256 thr.
__global__ __launch_bounds__(256) void fuse_weights_kernel(
        const float* __restrict__ Wz, const float* __restrict__ Wr,
        const float* __restrict__ Wh,
        const float* __restrict__ lzW, const float* __restrict__ lrW,
        const float* __restrict__ lhW,
        ushort* __restrict__ BT) {
    int g = blockIdx.x, kt = blockIdx.y;
    const float* W  = (g == 0) ? Wz  : (g == 1) ? Wr  : Wh;
    const float* lW = (g == 0) ? lzW : (g == 1) ? lrW : lhW;
    int t = threadIdx.x;
    int j = t & 127, kh = t >> 7;          // kh in {0,1}
    int k0 = kt * 8 + kh * 4;
    float m0 = 0.f, m1 = 0.f, m2 = 0.f, m3 = 0.f;
    for (int mm = 0; mm < 128; ++mm) {
        float lv = lW[mm * 128 + j];       // coalesced across j
        m0 += W[(k0 + 0) * 128 + mm] * lv; // wave-uniform -> broadcast
        m1 += W[(k0 + 1) * 128 + mm] * lv;
        m2 += W[(k0 + 2) * 128 + mm] * lv;
        m3 += W[(k0 + 3) * 128 + mm] * lv;
    }
    ushort* dstc = BT + ((size_t)g * 128 + j) * 256;
    dstc[k0 + 0] = f2bf(m0); dstc[k0 + 1] = f2bf(m1);
    dstc[k0 + 2] = f2bf(m2); dstc[k0 + 3] = f2bf(m3);
#pragma unroll
    for (int u = 0; u < 4; ++u) {
        int mm = k0 + u;
        dstc[128 + mm] = f2bf(lW[(128 + mm) * 128 + j]);
    }
}

// lb2[g][j] = lgb[j] + sum_m bg[m]*lgW_top[m][j]
__global__ __launch_bounds__(128) void lb2_kernel(
        const float* __restrict__ lzW, const float* __restrict__ lrW,
        const float* __restrict__ lhW,
        const float* __restrict__ bz, const float* __restrict__ br,
        const float* __restrict__ bh,
        const float* __restrict__ lzb, const float* __restrict__ lrb,
        const float* __restrict__ lhb,
        float* __restrict__ lb2) {
    int g = blockIdx.x, j = threadIdx.x;
    const float* lW = (g == 0) ? lzW : (g == 1) ? lrW : lhW;
    const float* bg = (g == 0) ? bz  : (g == 1) ? br  : bh;
    const float* lb = (g == 0) ? lzb : (g == 1) ? lrb : lhb;
    float s = lb[j];
    for (int mm = 0; mm < 128; ++mm) s += bg[mm] * lW[mm * 128 + j];
    lb2[g * 128 + j] = s;
}

// agg: 2 adjacent nodes per wave, dual 8-deep gather pipelines, es prefetch.
// aggb[i,:] = bf16( dinv_i * (dinv_i*nf_i + sum_e (w*dinv_s)*nf_s) )
__global__ __launch_bounds__(256) void agg_feat_kernel(
        const unsigned* __restrict__ nfb32, const float* __restrict__ dinv,
        const int* __restrict__ row_ptr, const int2* __restrict__ es,
        unsigned* __restrict__ aggb32, int n) {
    int t = threadIdx.x & 63;            // column pair
    int grp = threadIdx.x >> 6;
    int iA = blockIdx.x * 8 + grp * 2;
    if (iA >= n) return;
    int iB = iA + 1;
    bool hasB = iB < n;
    float dA = dinv[iA];
    float dB = hasB ? dinv[iB] : 0.0f;
    unsigned sA = nfb32[(size_t)iA * 64 + t];
    unsigned sB = hasB ? nfb32[(size_t)iB * 64 + t] : 0u;
    float a0A = dA * bflo(sA), a1A = dA * bfhi(sA);
    float a0B = dB * bflo(sB), a1B = dB * bfhi(sB);
    int eA = row_ptr[iA];
    int e1A = row_ptr[iA + 1];
    int eB = e1A;                                  // CSR adjacency
    int e1B = hasB ? row_ptr[iB + 1] : e1A;

    int2 zed; zed.x = 0; zed.y = 0;
    int2 bufA[8], bufB[8];
#pragma unroll
    for (int u = 0; u < 8; ++u) {
        int ea = eA + u;
        bufA[u] = (ea < e1A) ? es[ea] : zed;
        int eb = eB + u;
        bufB[u] = (eb < e1B) ? es[eb] : zed;
    }
    while (eA < e1A || eB < e1B) {
        unsigned vA[8], vB[8];
        float wA[8], wB[8];
#pragma unroll
        for (int u = 0; u < 8; ++u) {
            vA[u] = nfb32[(size_t)bufA[u].x * 64 + t];
            wA[u] = __int_as_float(bufA[u].y);
            vB[u] = nfb32[(size_t)bufB[u].x * 64 + t];
            wB[u] = __int_as_float(bufB[u].y);
        }
        int nA = eA + 8, nB = eB + 8;
#pragma unroll
        for (int u = 0; u < 8; ++u) {
            int ea = nA + u;
            bufA[u] = (eA < e1A && ea < e1A) ? es[ea] : zed;
            int eb = nB + u;
            bufB[u] = (eB < e1B && eb < e1B) ? es[eb] : zed;
        }
#pragma unroll
        for (int u = 0; u < 8; ++u) {
            a0A += wA[u] * bflo(vA[u]);
            a1A += wA[u] * bfhi(vA[u]);
            a0B += wB[u] * bflo(vB[u]);
            a1B += wB[u] * bfhi(vB[u]);
        }
        eA = min(nA, e1A);
        eB = min(nB, e1B);
    }
    a0A *= dA; a1A *= dA;
    a0B *= dB; a1B *= dB;
    aggb32[(size_t)iA * 64 + t] = (unsigned)f2bf(a0A) | ((unsigned)f2bf(a1A) << 16);
    if (hasB)
        aggb32[(size_t)iB * 64 + t] = (unsigned)f2bf(a0B) | ((unsigned)f2bf(a1B) << 16);
}

// Fused GRU, merged Z+R phase: A=[Aag|Ah0] is read ONCE and feeds 4 MFMAs per
// fragment (z0,z1,r0,r1). B-frags double-buffered per-ks. Then hq=sig(r)*h0
// -> Ahq, barrier, HT phase (A=[Aag|Ahq]) with its own B dbuf.
#define BADDR(g, cf, ks) (BT + (size_t)((g) * 128 + c0 + (cf) * 16 + rlo) * 256 \
                          + (ks) * 32 + koff)
__global__ __launch_bounds__(256) void gru_fused_kernel(
        const ushort* __restrict__ aggb, const ushort* __restrict__ h0b,
        const ushort* __restrict__ BT, const float* __restrict__ lb2,
        float* __restrict__ hout, int n) {
    __shared__ ushort Aag[64][136];
    __shared__ ushort Ah0[64][136];
    __shared__ ushort Ahq[64][136];
    int t = threadIdx.x;
    int i0 = blockIdx.x * 64;

    int w = t >> 6, lane = t & 63;
    int rlo = lane & 15, koff = (lane >> 4) * 8, rbase = (lane >> 4) * 4;
    int c0 = w * 32;

    // issue first ZR B-frags before staging (latency hidden under stage+barrier)
    short8 bz0 = *(const short8*)BADDR(0, 0, 0);
    short8 bz1 = *(const short8*)BADDR(0, 1, 0);
    short8 br0 = *(const short8*)BADDR(1, 0, 0);
    short8 br1 = *(const short8*)BADDR(1, 1, 0);

    for (int c = t; c < 1024; c += 256) {
        int row = c >> 4, c8 = c & 15;
        size_t gp = (size_t)(i0 + row) * HD + c8 * 8;
        *(short8*)&Aag[row][c8 * 8] = *(const short8*)(aggb + gp);
        *(short8*)&Ah0[row][c8 * 8] = *(const short8*)(h0b + gp);
    }
    __syncthreads();

    const f32x4 zero4 = {0.f, 0.f, 0.f, 0.f};
    f32x4 accz[4][2], accr[4][2];
#pragma unroll
    for (int rf = 0; rf < 4; ++rf) {
        accz[rf][0] = zero4; accz[rf][1] = zero4;
        accr[rf][0] = zero4; accr[rf][1] = zero4;
    }

    // ===== merged ZR phase: 4 MFMAs per A-fragment, B dbuf per ks =====
#pragma unroll
    for (int ks = 0; ks < 8; ++ks) {
        short8 nz0, nz1, nr0, nr1;
        if (ks < 7) {
            nz0 = *(const short8*)BADDR(0, 0, ks + 1);
            nz1 = *(const short8*)BADDR(0, 1, ks + 1);
            nr0 = *(const short8*)BADDR(1, 0, ks + 1);
            nr1 = *(const short8*)BADDR(1, 1, ks + 1);
        }
#pragma unroll
        for (int rf = 0; rf < 4; ++rf) {
            short8 af = (ks < 4)
                ? *(const short8*)&Aag[rf * 16 + rlo][ks * 32 + koff]
                : *(const short8*)&Ah0[rf * 16 + rlo][(ks - 4) * 32 + koff];
            accz[rf][0] = __builtin_amdgcn_mfma_f32_16x16x32_bf16(af, bz0, accz[rf][0], 0, 0, 0);
            accz[rf][1] = __builtin_amdgcn_mfma_f32_16x16x32_bf16(af, bz1, accz[rf][1], 0, 0, 0);
            accr[rf][0] = __builtin_amdgcn_mfma_f32_16x16x32_bf16(af, br0, accr[rf][0], 0, 0, 0);
            accr[rf][1] = __builtin_amdgcn_mfma_f32_16x16x32_bf16(af, br1, accr[rf][1], 0, 0, 0);
        }
        if (ks < 7) { bz0 = nz0; bz1 = nz1; br0 = nr0; br1 = nr1; }
    }

    // epilogue ZR: z -> regs; hq = sigmoid(r)*h0 -> Ahq
    float zv[4][2][4];
#pragma unroll
    for (int rf = 0; rf < 4; ++rf)
#pragma unroll
        for (int cf = 0; cf < 2; ++cf) {
            int lc = c0 + cf * 16 + rlo;
            float bvz = lb2[lc];
            float bvr = lb2[128 + lc];
#pragma unroll
            for (int i = 0; i < 4; ++i) {
                int row = rf * 16 + rbase + i;
                zv[rf][cf][i] = fast_sigmoid(accz[rf][cf][i] + bvz);
                float r = fast_sigmoid(accr[rf][cf][i] + bvr);
                Ahq[row][lc] = f2bf(r * bf2f(Ah0[row][lc]));
            }
        }
    // pre-issue HT's first B-frags to hide latency under the barrier
    short8 bh0 = *(const short8*)BADDR(2, 0, 0);
    short8 bh1 = *(const short8*)BADDR(2, 1, 0);
    __syncthreads();   // hq visible to all waves

    // ===== HT phase: A = [Aag | Ahq], B dbuf per ks =====
    f32x4 acch[4][2];
#pragma unroll
    for (int rf = 0; rf < 4; ++rf) { acch[rf][0] = zero4; acch[rf][1] = zero4; }
#pragma unroll
    for (int ks = 0; ks < 8; ++ks) {
        short8 nh0, nh1;
        if (ks < 7) {
            nh0 = *(const short8*)BADDR(2, 0, ks + 1);
            nh1 = *(const short8*)BADDR(2, 1, ks + 1);
        }
#pragma unroll
        for (int rf = 0; rf < 4; ++rf) {
            short8 af = (ks < 4)
                ? *(const short8*)&Aag[rf * 16 + rlo][ks * 32 + koff]
                : *(const short8*)&Ahq[rf * 16 + rlo][(ks - 4) * 32 + koff];
            acch[rf][0] = __builtin_amdgcn_mfma_f32_16x16x32_bf16(af, bh0, acch[rf][0], 0, 0, 0);
            acch[rf][1] = __builtin_amdgcn_mfma_f32_16x16x32_bf16(af, bh1, acch[rf][1], 0, 0, 0);
        }
        if (ks < 7) { bh0 = nh0; bh1 = nh1; }
    }
#pragma unroll
    for (int rf = 0; rf < 4; ++rf)
#pragma unroll
        for (int cf = 0; cf < 2; ++cf) {
            int lc = c0 + cf * 16 + rlo;
            float bv = lb2[256 + lc];
#pragma unroll
            for (int i = 0; i < 4; ++i) {
                int row = rf * 16 + rbase + i;
                int grow = i0 + row;
                if (grow < n) {
                    float ht = fast_tanh(acch[rf][cf][i] + bv);
                    float z = zv[rf][cf][i];
                    float h0v = bf2f(Ah0[row][lc]);
                    hout[(size_t)grow * HD + lc] = z * h0v + (1.0f - z) * ht;
                }
            }
        }
}

__global__ __launch_bounds__(128) void pool_kernel(
        const float* __restrict__ hout, const int* __restrict__ nids,
        float* pooled, int U) {
    int t = threadIdx.x;
    float pa = 0.0f;
    for (int u = blockIdx.x; u < U; u += gridDim.x) {
        int nid = nids[u];
        pa += fmaxf(hout[(size_t)nid * HD + t], 0.0f);
    }
    atomicAdd(&pooled[t], pa);
}

__global__ __launch_bounds__(128) void decoder_kernel(
        const float* __restrict__ pooled, float invU,
        const float* __restrict__ linW, const float* __restrict__ linb,
        const float* __restrict__ dnW, const float* __restrict__ dnb,
        const float* __restrict__ outW, const float* __restrict__ outb,
        float* pred, int C) {
    __shared__ float sh[HD];
    int t = threadIdx.x;
    sh[t] = pooled[t] * invU;
    __syncthreads();
    float v = linb[t];
    for (int k = 0; k < HD; ++k) v += sh[k] * linW[k * HD + t];
    __syncthreads();
    sh[t] = v;
    __syncthreads();
    float d = dnb[t];
    for (int k = 0; k < HD; ++k) d += sh[k] * dnW[k * HD + t];
    d = fmaxf(d, 0.0f);
    __syncthreads();
    sh[t] = d;
    __syncthreads();
    if (t < C) {
        float p = outb[t];
        for (int k = 0; k < HD; ++k) p += sh[k] * outW[k * C + t];
        pred[t] = 1.0f / (1.0f + expf(-p));
    }
}

extern "C" void kernel_launch(void* const* d_in, const int* in_sizes, int n_in,
                              void* d_out, int out_size, void* d_ws, size_t ws_size,
                              hipStream_t stream) {
    const float* node_feat = (const float*)d_in[0];
    const float* edge_w    = (const float*)d_in[1];
    const float* h0        = (const float*)d_in[2];
    const float* Wz  = (const float*)d_in[3];  const float* bz  = (const float*)d_in[4];
    const float* Wr  = (const float*)d_in[5];  const float* br  = (const float*)d_in[6];
    const float* Wh  = (const float*)d_in[7];  const float* bh  = (const float*)d_in[8];
    const float* lzW = (const float*)d_in[9];  const float* lzb = (const float*)d_in[10];
    const float* lrW = (const float*)d_in[11]; const float* lrb = (const float*)d_in[12];
    const float* lhW = (const float*)d_in[13]; const float* lhb = (const float*)d_in[14];
    const float* linW= (const float*)d_in[15]; const float* linb= (const float*)d_in[16];
    const float* dnW = (const float*)d_in[17]; const float* dnb = (const float*)d_in[18];
    const float* outW= (const float*)d_in[19]; const float* outb= (const float*)d_in[20];
    const int* src  = (const int*)d_in[21];
    const int* dst  = (const int*)d_in[22];
    const int* nids = (const int*)d_in[23];

    const int N = in_sizes[2] / HD;
    const int E = in_sizes[1];
    const int U = in_sizes[23];
    const int C = in_sizes[20];
    const int NP = (N + 127) & ~127;    // row-padded
    const int NB1K = (N + 1023) / 1024; // scan blocks
    const int NR = (N + RSIZE - 1) / RSIZE;       // ranges
    const int NPAD = NR * RSIZE;
    int NEC = 64;                                  // edge chunks
    {   // keep per-chunk counts < 65536 for packed ushort ranks
        int minc = (E + 65535) / 65536;
        if (NEC < minc) NEC = minc;
    }
    const int EC = (E + NEC - 1) / NEC;

    float* out  = (float*)d_out;
    float* pred = out;          // [C]
    float* hout = out + C;      // [N,H]

    // workspace layout (16B-aligned chunks)
    char* p = (char*)d_ws;
    auto alloc = [&](size_t bytes) { char* r = p; p += (bytes + 15) & ~(size_t)15; return r; };
    float* dinv   = (float*)alloc((size_t)N * 4);
    float* pooled = (float*)alloc(HD * 4);
    int*   counts = (int*)alloc((size_t)N * 4);
    int*   row_ptr= (int*)alloc((size_t)(N + 1) * 4);
    int2*  es     = (int2*)alloc((size_t)E * 8);
    int*   bsums  = (int*)alloc((size_t)1024 * 4);
    int*   pc     = (int*)alloc((size_t)NEC * NPAD * 4);
    float* pw     = (float*)alloc((size_t)NEC * NPAD * 4);
    ushort* nfb   = (ushort*)alloc((size_t)NP * HD * 2);
    ushort* aggb  = (ushort*)alloc((size_t)NP * HD * 2);
    ushort* h0b   = (ushort*)alloc((size_t)NP * HD * 2);
    ushort* BT    = (ushort*)alloc((size_t)3 * 128 * 256 * 2);
    float* lb2    = (float*)alloc(384 * 4);

    hipMemsetAsync(pooled, 0, HD * sizeof(float), stream);

    int prep_items = N * (HD / 8);
    prep_kernel<<<(prep_items + 255) / 256, 256, 0, stream>>>(node_feat, h0, nfb, h0b, N);
    hist_lds_kernel<<<NR * NEC, 256, 0, stream>>>(dst, edge_w, pc, pw, NPAD, NR, EC, E);
    reduce_hist_kernel<<<(N + 255) / 256, 256, 0, stream>>>(pc, pw, counts, dinv,
                                                            NPAD, NEC, N);
    scan_partial_kernel<<<NB1K, 256, 0, stream>>>(counts, bsums, N);
    scan_bsums_kernel<<<1, 1024, 0, stream>>>(bsums, row_ptr + N, NB1K);
    scan_final_kernel<<<NB1K, 256, 0, stream>>>(counts, bsums, row_ptr, N);
    col_scan_kernel<<<(N + 255) / 256, 256, 0, stream>>>(row_ptr, pc, NPAD, NEC, N);
    fill2d_kernel<<<NEC * NR, 512, 0, stream>>>(src, dst, edge_w, dinv, pc,
                                                es, NPAD, NR, EC, E);
    dim3 fg(3, 16);
    fuse_weights_kernel<<<fg, 256, 0, stream>>>(Wz, Wr, Wh, lzW, lrW, lhW, BT);
    lb2_kernel<<<3, 128, 0, stream>>>(lzW, lrW, lhW, bz, br, bh, lzb, lrb, lhb, lb2);
    agg_feat_kernel<<<(N + 7) / 8, 256, 0, stream>>>(
        (const unsigned*)nfb, dinv, row_ptr, es, (unsigned*)aggb, N);
    gru_fused_kernel<<<NP / 64, 256, 0, stream>>>(aggb, h0b, BT, lb2, hout, N);
    pool_kernel<<<512, 128, 0, stream>>>(hout, nids, pooled, U);
    decoder_kernel<<<1, 128, 0, stream>>>(pooled, 1.0f / (float)U,
                                          linW, linb, dnW, dnb, outW, outb, pred, C);
}

// Round 15
// 261.902 us; speedup vs baseline: 1.0316x; 1.0316x over previous
//
#include <hip/hip_runtime.h>
#include <math.h>

// TGCN: bf16 feature-space GCN aggregation (fp32 accum) -> single fused GRU
// kernel (merged Z+R phase sharing A-reads, double-buffered B-frags).
// CSR-by-dst with ZERO global atomics; interleaved int2 {src, w*dinv_s}.
// agg: uint2 gathers (2 edges per wave-instruction via half-waves).

#define HD 128
#define RBITS 13
#define RSIZE 8192          // nodes per histogram/fill range

typedef __attribute__((ext_vector_type(8))) short short8;
typedef __attribute__((ext_vector_type(4))) float f32x4;

__device__ __forceinline__ ushort f2bf(float f) {
    union { float f; unsigned u; } v; v.f = f;
    unsigned r = (v.u + 0x7FFFu + ((v.u >> 16) & 1u)) >> 16;
    return (ushort)r;
}
__device__ __forceinline__ float bf2f(ushort h) {
    union { unsigned u; float f; } v; v.u = ((unsigned)h) << 16;
    return v.f;
}
__device__ __forceinline__ float bflo(unsigned u) {
    union { unsigned u; float f; } v; v.u = u << 16; return v.f;
}
__device__ __forceinline__ float bfhi(unsigned u) {
    union { unsigned u; float f; } v; v.u = u & 0xFFFF0000u; return v.f;
}
__device__ __forceinline__ float fast_sigmoid(float x) {
    return 1.0f / (1.0f + __expf(-x));
}
__device__ __forceinline__ float fast_tanh(float x) {
    float e = __expf(-2.0f * fabsf(x));
    float m = (1.0f - e) / (1.0f + e);
    return copysignf(m, x);
}

// nf -> bf16, h0 -> bf16 (vectorized)
__global__ void prep_kernel(const float* __restrict__ nf, const float* __restrict__ h0,
                            ushort* __restrict__ nfb, ushort* __restrict__ h0b, int n) {
    int idx = blockIdx.x * 256 + threadIdx.x;
    int total8 = n * (HD / 8);
    if (idx < total8) {
        const float4* p = (const float4*)(nf + (size_t)idx * 8);
        float4 x = p[0], y = p[1];
        short8 o;
        o[0] = (short)f2bf(x.x); o[1] = (short)f2bf(x.y);
        o[2] = (short)f2bf(x.z); o[3] = (short)f2bf(x.w);
        o[4] = (short)f2bf(y.x); o[5] = (short)f2bf(y.y);
        o[6] = (short)f2bf(y.z); o[7] = (short)f2bf(y.w);
        *(short8*)(nfb + (size_t)idx * 8) = o;
        const float4* q = (const float4*)(h0 + (size_t)idx * 8);
        float4 a = q[0], b = q[1];
        short8 o2;
        o2[0] = (short)f2bf(a.x); o2[1] = (short)f2bf(a.y);
        o2[2] = (short)f2bf(a.z); o2[3] = (short)f2bf(a.w);
        o2[4] = (short)f2bf(b.x); o2[5] = (short)f2bf(b.y);
        o2[6] = (short)f2bf(b.z); o2[7] = (short)f2bf(b.w);
        *(short8*)(h0b + (size_t)idx * 8) = o2;
    }
}

// LDS-privatized histogram. Block (r = bid%NR, c = bid/NR).
__global__ __launch_bounds__(256) void hist_lds_kernel(
        const int* __restrict__ dst, const float* __restrict__ w,
        int* __restrict__ pc, float* __restrict__ pw,
        int NPAD, int NR, int EC, int E) {
    __shared__ int lc[RSIZE];
    __shared__ float lw[RSIZE];
    int r = blockIdx.x % NR;
    int c = blockIdx.x / NR;
    int t = threadIdx.x;
    for (int b = t; b < RSIZE; b += 256) { lc[b] = 0; lw[b] = 0.0f; }
    __syncthreads();
    int base = c * EC;
    int end = min(base + EC, E);
    int rbase = r << RBITS;
    for (int e = base + t; e < end; e += 256) {
        int d = dst[e];
        float wv = w[e];
        if ((d >> RBITS) == r) {
            atomicAdd(&lc[d - rbase], 1);
            atomicAdd(&lw[d - rbase], wv);
        }
    }
    __syncthreads();
    size_t o = (size_t)c * NPAD + rbase;
    for (int b = t; b < RSIZE; b += 256) {
        pc[o + b] = lc[b];
        pw[o + b] = lw[b];
    }
}

// counts[i] = sum_c pc[c][i];  dinv[i] = rsqrt(1 + sum_c pw[c][i])
__global__ __launch_bounds__(256) void reduce_hist_kernel(
        const int* __restrict__ pc, const float* __restrict__ pw,
        int* __restrict__ counts, float* __restrict__ dinv,
        int NPAD, int NEC, int N) {
    int i = blockIdx.x * 256 + threadIdx.x;
    if (i >= N) return;
    int ctot = 0;
    float d = 1.0f;   // self-loop
    for (int c = 0; c < NEC; ++c) {
        ctot += pc[(size_t)c * NPAD + i];
        d += pw[(size_t)c * NPAD + i];
    }
    counts[i] = ctot;
    dinv[i] = (d > 0.0f) ? rsqrtf(d) : 0.0f;
}

// ---- hierarchical scan ----
__global__ __launch_bounds__(256) void scan_partial_kernel(
        const int* __restrict__ counts, int* __restrict__ bsums, int n) {
    __shared__ int ws[4];
    int b = blockIdx.x, t = threadIdx.x;
    int idx = b * 1024 + t * 4;
    int4 v = {0, 0, 0, 0};
    if (idx + 3 < n) v = *(const int4*)(counts + idx);
    else {
        if (idx < n) v.x = counts[idx];
        if (idx + 1 < n) v.y = counts[idx + 1];
        if (idx + 2 < n) v.z = counts[idx + 2];
        if (idx + 3 < n) v.w = counts[idx + 3];
    }
    int s = v.x + v.y + v.z + v.w;
    for (int off = 1; off < 64; off <<= 1) s += __shfl_xor(s, off, 64);
    if ((t & 63) == 0) ws[t >> 6] = s;
    __syncthreads();
    if (t == 0) bsums[b] = ws[0] + ws[1] + ws[2] + ws[3];
}

__global__ __launch_bounds__(1024) void scan_bsums_kernel(
        int* __restrict__ bsums, int* __restrict__ rp_total, int nb) {
    __shared__ int ws[16];
    int t = threadIdx.x;
    int v = (t < nb) ? bsums[t] : 0;
    int lane = t & 63, wid = t >> 6;
    int x = v;
    for (int off = 1; off < 64; off <<= 1) {
        int y = __shfl_up(x, off, 64);
        if (lane >= off) x += y;
    }
    if (lane == 63) ws[wid] = x;
    __syncthreads();
    if (wid == 0) {
        int s = (lane < 16) ? ws[lane] : 0;
        for (int off = 1; off < 16; off <<= 1) {
            int y = __shfl_up(s, off, 64);
            if (lane >= off) s += y;
        }
        if (lane < 16) ws[lane] = s;
    }
    __syncthreads();
    int excl = x - v + ((wid == 0) ? 0 : ws[wid - 1]);
    if (t < nb) bsums[t] = excl;
    if (t == nb - 1) *rp_total = excl + v;
}

__global__ __launch_bounds__(256) void scan_final_kernel(
        const int* __restrict__ counts, const int* __restrict__ bsums,
        int* __restrict__ row_ptr, int n) {
    __shared__ int ws[4];
    int b = blockIdx.x, t = threadIdx.x;
    int idx = b * 1024 + t * 4;
    int4 v = {0, 0, 0, 0};
    if (idx + 3 < n) v = *(const int4*)(counts + idx);
    else {
        if (idx < n) v.x = counts[idx];
        if (idx + 1 < n) v.y = counts[idx + 1];
        if (idx + 2 < n) v.z = counts[idx + 2];
        if (idx + 3 < n) v.w = counts[idx + 3];
    }
    int s = v.x + v.y + v.z + v.w;
    int lane = t & 63, wid = t >> 6;
    int x = s;
    for (int off = 1; off < 64; off <<= 1) {
        int y = __shfl_up(x, off, 64);
        if (lane >= off) x += y;
    }
    if (lane == 63) ws[wid] = x;
    __syncthreads();
    int woff = 0;
    for (int wv = 0; wv < wid; ++wv) woff += ws[wv];
    int run = bsums[b] + woff + x - s;
    int4 rp;
    rp.x = run; rp.y = run + v.x; rp.z = rp.y + v.y; rp.w = rp.z + v.z;
    if (idx + 3 < n) {
        *(int4*)(row_ptr + idx) = rp;
    } else {
        if (idx < n) row_ptr[idx] = rp.x;
        if (idx + 1 < n) row_ptr[idx + 1] = rp.y;
        if (idx + 2 < n) row_ptr[idx + 2] = rp.z;
        if (idx + 3 < n) row_ptr[idx + 3] = rp.w;
    }
}

// pc[c][d] (counts) -> per-chunk CSR base offsets (in place)
__global__ __launch_bounds__(256) void col_scan_kernel(
        const int* __restrict__ row_ptr, int* __restrict__ pc,
        int NPAD, int NEC, int n) {
    int i = blockIdx.x * 256 + threadIdx.x;
    if (i >= n) return;
    int run = row_ptr[i];
    for (int c = 0; c < NEC; ++c) {
        size_t idx = (size_t)c * NPAD + i;
        int v = pc[idx];
        pc[idx] = run;
        run += v;
    }
}

// fill: block (c,r); pco range-slice preloaded into LDS; packed ushort ranks;
// ONE int2 {src, w*dinv_s} store per edge.
__global__ __launch_bounds__(512) void fill2d_kernel(
        const int* __restrict__ src, const int* __restrict__ dst,
        const float* __restrict__ w, const float* __restrict__ dinv,
        const int* __restrict__ pc, int2* __restrict__ es,
        int NPAD, int NR, int EC, int E) {
    __shared__ int po[RSIZE];            // 32KB preloaded base offsets
    __shared__ unsigned pk[RSIZE / 2];   // 16KB packed ushort cursors
    int r = blockIdx.x % NR;
    int c = blockIdx.x / NR;
    int t = threadIdx.x;
    const int* __restrict__ pco = pc + (size_t)c * NPAD + (r << RBITS);
    for (int b = t; b < RSIZE / 2; b += 512) pk[b] = 0u;
    for (int b = t; b < RSIZE; b += 512) po[b] = pco[b];
    __syncthreads();
    int base = c * EC;
    int end = min(base + EC, E);
    int rbase = r << RBITS;
    for (int e = base + t; e < end; e += 512) {
        int d = dst[e];
        if ((d >> RBITS) == r) {
            int dl = d - rbase;
            unsigned sh = (dl & 1) * 16;
            unsigned old = atomicAdd(&pk[dl >> 1], 1u << sh);
            int rank = (int)((old >> sh) & 0xFFFFu);
            int pos = po[dl] + rank;
            int s = src[e];
            float nv = dinv[s] * w[e];        // dinv[d] applied in agg epilogue
            int2 ev;
            ev.x = s;
            ev.y = __float_as_int(nv);
            es[pos] = ev;
        }
    }
}

// Fused-weight build, parallel+coalesced. grid (3,16), 256 thr.
__global__ __launch_bounds__(256) void fuse_weights_kernel(
        const float* __restrict__ Wz, const float* __restrict__ Wr,
        const float* __restrict__ Wh,
        const float* __restrict__ lzW, const float* __restrict__ lrW,
        const float* __restrict__ lhW,
        ushort* __restrict__ BT) {
    int g = blockIdx.x, kt = blockIdx.y;
    const float* W  = (g == 0) ? Wz  : (g == 1) ? Wr  : Wh;
    const float* lW = (g == 0) ? lzW : (g == 1) ? lrW : lhW;
    int t = threadIdx.x;
    int j = t & 127, kh = t >> 7;          // kh in {0,1}
    int k0 = kt * 8 + kh * 4;
    float m0 = 0.f, m1 = 0.f, m2 = 0.f, m3 = 0.f;
    for (int mm = 0; mm < 128; ++mm) {
        float lv = lW[mm * 128 + j];       // coalesced across j
        m0 += W[(k0 + 0) * 128 + mm] * lv; // wave-uniform -> broadcast
        m1 += W[(k0 + 1) * 128 + mm] * lv;
        m2 += W[(k0 + 2) * 128 + mm] * lv;
        m3 += W[(k0 + 3) * 128 + mm] * lv;
    }
    ushort* dstc = BT + ((size_t)g * 128 + j) * 256;
    dstc[k0 + 0] = f2bf(m0); dstc[k0 + 1] = f2bf(m1);
    dstc[k0 + 2] = f2bf(m2); dstc[k0 + 3] = f2bf(m3);
#pragma unroll
    for (int u = 0; u < 4; ++u) {
        int mm = k0 + u;
        dstc[128 + mm] = f2bf(lW[(128 + mm) * 128 + j]);
    }
}

// lb2[g][j] = lgb[j] + sum_m bg[m]*lgW_top[m][j]
__global__ __launch_bounds__(128) void lb2_kernel(
        const float* __restrict__ lzW, const float* __restrict__ lrW,
        const float* __restrict__ lhW,
        const float* __restrict__ bz, const float* __restrict__ br,
        const float* __restrict__ bh,
        const float* __restrict__ lzb, const float* __restrict__ lrb,
        const float* __restrict__ lhb,
        float* __restrict__ lb2) {
    int g = blockIdx.x, j = threadIdx.x;
    const float* lW = (g == 0) ? lzW : (g == 1) ? lrW : lhW;
    const float* bg = (g == 0) ? bz  : (g == 1) ? br  : bh;
    const float* lb = (g == 0) ? lzb : (g == 1) ? lrb : lhb;
    float s = lb[j];
    for (int mm = 0; mm < 128; ++mm) s += bg[mm] * lW[mm * 128 + j];
    lb2[g * 128 + j] = s;
}

// agg: ONE node per wave; half-waves take alternating 8-edge batches; each
// lane gathers uint2 (8B) so a wave covers 2 edge-rows per instruction.
// Cross-half combine via shfl_xor(32); lanes<32 pack+write uint2.
// aggb[i,:] = bf16( dinv_i * (dinv_i*nf_i + sum_e (w*dinv_s)*nf_s) )
__global__ __launch_bounds__(256) void agg_feat_kernel(
        const uint2* __restrict__ nfb2, const float* __restrict__ dinv,
        const int* __restrict__ row_ptr, const int2* __restrict__ es,
        uint2* __restrict__ aggb2, int n) {
    int lane = threadIdx.x & 63;
    int wv = threadIdx.x >> 6;
    int i = blockIdx.x * 4 + wv;
    if (i >= n) return;
    int sub = lane & 31;
    int half = lane >> 5;
    float dA = dinv[i];
    float a0 = 0.f, a1 = 0.f, a2 = 0.f, a3 = 0.f;
    int e0 = row_ptr[i], e1 = row_ptr[i + 1];
    int iters = (e1 - e0 + 15) >> 4;

    int2 zed; zed.x = 0; zed.y = 0;
    int e = e0 + half * 8;            // this half's first batch
    int2 buf[8];
#pragma unroll
    for (int u = 0; u < 8; ++u) {
        int ee = e + u;
        buf[u] = (ee < e1) ? es[ee] : zed;
    }
    for (int it = 0; it < iters; ++it) {
        uint2 v[8]; float w[8];
#pragma unroll
        for (int u = 0; u < 8; ++u) {
            v[u] = nfb2[(size_t)buf[u].x * 32 + sub];
            w[u] = __int_as_float(buf[u].y);
        }
        int en = e + 16;
#pragma unroll
        for (int u = 0; u < 8; ++u) {
            int ee = en + u;
            buf[u] = (it + 1 < iters && ee < e1) ? es[ee] : zed;
        }
#pragma unroll
        for (int u = 0; u < 8; ++u) {
            a0 += w[u] * bflo(v[u].x);
            a1 += w[u] * bfhi(v[u].x);
            a2 += w[u] * bflo(v[u].y);
            a3 += w[u] * bfhi(v[u].y);
        }
        e = en;
    }
    // combine halves
    a0 += __shfl_xor(a0, 32, 64);
    a1 += __shfl_xor(a1, 32, 64);
    a2 += __shfl_xor(a2, 32, 64);
    a3 += __shfl_xor(a3, 32, 64);
    if (half == 0) {
        uint2 self = nfb2[(size_t)i * 32 + sub];
        float f0 = dA * (dA * bflo(self.x) + a0);
        float f1 = dA * (dA * bfhi(self.x) + a1);
        float f2 = dA * (dA * bflo(self.y) + a2);
        float f3 = dA * (dA * bfhi(self.y) + a3);
        uint2 o;
        o.x = (unsigned)f2bf(f0) | ((unsigned)f2bf(f1) << 16);
        o.y = (unsigned)f2bf(f2) | ((unsigned)f2bf(f3) << 16);
        aggb2[(size_t)i * 32 + sub] = o;
    }
}

// Fused GRU, merged Z+R phase sharing A-reads; B-frags double-buffered.
#define BADDR(g, cf, ks) (BT + (size_t)((g) * 128 + c0 + (cf) * 16 + rlo) * 256 \
                          + (ks) * 32 + koff)
__global__ __launch_bounds__(256) void gru_fused_kernel(
        const ushort* __restrict__ aggb, const ushort* __restrict__ h0b,
        const ushort* __restrict__ BT, const float* __restrict__ lb2,
        float* __restrict__ hout, int n) {
    __shared__ ushort Aag[64][136];
    __shared__ ushort Ah0[64][136];
    __shared__ ushort Ahq[64][136];
    int t = threadIdx.x;
    int i0 = blockIdx.x * 64;

    int w = t >> 6, lane = t & 63;
    int rlo = lane & 15, koff = (lane >> 4) * 8, rbase = (lane >> 4) * 4;
    int c0 = w * 32;

    short8 bz0 = *(const short8*)BADDR(0, 0, 0);
    short8 bz1 = *(const short8*)BADDR(0, 1, 0);
    short8 br0 = *(const short8*)BADDR(1, 0, 0);
    short8 br1 = *(const short8*)BADDR(1, 1, 0);

    for (int c = t; c < 1024; c += 256) {
        int row = c >> 4, c8 = c & 15;
        size_t gp = (size_t)(i0 + row) * HD + c8 * 8;
        *(short8*)&Aag[row][c8 * 8] = *(const short8*)(aggb + gp);
        *(short8*)&Ah0[row][c8 * 8] = *(const short8*)(h0b + gp);
    }
    __syncthreads();

    const f32x4 zero4 = {0.f, 0.f, 0.f, 0.f};
    f32x4 accz[4][2], accr[4][2];
#pragma unroll
    for (int rf = 0; rf < 4; ++rf) {
        accz[rf][0] = zero4; accz[rf][1] = zero4;
        accr[rf][0] = zero4; accr[rf][1] = zero4;
    }

#pragma unroll
    for (int ks = 0; ks < 8; ++ks) {
        short8 nz0, nz1, nr0, nr1;
        if (ks < 7) {
            nz0 = *(const short8*)BADDR(0, 0, ks + 1);
            nz1 = *(const short8*)BADDR(0, 1, ks + 1);
            nr0 = *(const short8*)BADDR(1, 0, ks + 1);
            nr1 = *(const short8*)BADDR(1, 1, ks + 1);
        }
#pragma unroll
        for (int rf = 0; rf < 4; ++rf) {
            short8 af = (ks < 4)
                ? *(const short8*)&Aag[rf * 16 + rlo][ks * 32 + koff]
                : *(const short8*)&Ah0[rf * 16 + rlo][(ks - 4) * 32 + koff];
            accz[rf][0] = __builtin_amdgcn_mfma_f32_16x16x32_bf16(af, bz0, accz[rf][0], 0, 0, 0);
            accz[rf][1] = __builtin_amdgcn_mfma_f32_16x16x32_bf16(af, bz1, accz[rf][1], 0, 0, 0);
            accr[rf][0] = __builtin_amdgcn_mfma_f32_16x16x32_bf16(af, br0, accr[rf][0], 0, 0, 0);
            accr[rf][1] = __builtin_amdgcn_mfma_f32_16x16x32_bf16(af, br1, accr[rf][1], 0, 0, 0);
        }
        if (ks < 7) { bz0 = nz0; bz1 = nz1; br0 = nr0; br1 = nr1; }
    }

    float zv[4][2][4];
#pragma unroll
    for (int rf = 0; rf < 4; ++rf)
#pragma unroll
        for (int cf = 0; cf < 2; ++cf) {
            int lc = c0 + cf * 16 + rlo;
            float bvz = lb2[lc];
            float bvr = lb2[128 + lc];
#pragma unroll
            for (int i = 0; i < 4; ++i) {
                int row = rf * 16 + rbase + i;
                zv[rf][cf][i] = fast_sigmoid(accz[rf][cf][i] + bvz);
                float r = fast_sigmoid(accr[rf][cf][i] + bvr);
                Ahq[row][lc] = f2bf(r * bf2f(Ah0[row][lc]));
            }
        }
    short8 bh0 = *(const short8*)BADDR(2, 0, 0);
    short8 bh1 = *(const short8*)BADDR(2, 1, 0);
    __syncthreads();   // hq visible to all waves

    f32x4 acch[4][2];
#pragma unroll
    for (int rf = 0; rf < 4; ++rf) { acch[rf][0] = zero4; acch[rf][1] = zero4; }
#pragma unroll
    for (int ks = 0; ks < 8; ++ks) {
        short8 nh0, nh1;
        if (ks < 7) {
            nh0 = *(const short8*)BADDR(2, 0, ks + 1);
            nh1 = *(const short8*)BADDR(2, 1, ks + 1);
        }
#pragma unroll
        for (int rf = 0; rf < 4; ++rf) {
            short8 af = (ks < 4)
                ? *(const short8*)&Aag[rf * 16 + rlo][ks * 32 + koff]
                : *(const short8*)&Ahq[rf * 16 + rlo][(ks - 4) * 32 + koff];
            acch[rf][0] = __builtin_amdgcn_mfma_f32_16x16x32_bf16(af, bh0, acch[rf][0], 0, 0, 0);
            acch[rf][1] = __builtin_amdgcn_mfma_f32_16x16x32_bf16(af, bh1, acch[rf][1], 0, 0, 0);
        }
        if (ks < 7) { bh0 = nh0; bh1 = nh1; }
    }
#pragma unroll
    for (int rf = 0; rf < 4; ++rf)
#pragma unroll
        for (int cf = 0; cf < 2; ++cf) {
            int lc = c0 + cf * 16 + rlo;
            float bv = lb2[256 + lc];
#pragma unroll
            for (int i = 0; i < 4; ++i) {
                int row = rf * 16 + rbase + i;
                int grow = i0 + row;
                if (grow < n) {
                    float ht = fast_tanh(acch[rf][cf][i] + bv);
                    float z = zv[rf][cf][i];
                    float h0v = bf2f(Ah0[row][lc]);
                    hout[(size_t)grow * HD + lc] = z * h0v + (1.0f - z) * ht;
                }
            }
        }
}

__global__ __launch_bounds__(128) void pool_kernel(
        const float* __restrict__ hout, const int* __restrict__ nids,
        float* pooled, int U) {
    int t = threadIdx.x;
    float pa = 0.0f;
    for (int u = blockIdx.x; u < U; u += gridDim.x) {
        int nid = nids[u];
        pa += fmaxf(hout[(size_t)nid * HD + t], 0.0f);
    }
    atomicAdd(&pooled[t], pa);
}

__global__ __launch_bounds__(128) void decoder_kernel(
        const float* __restrict__ pooled, float invU,
        const float* __restrict__ linW, const float* __restrict__ linb,
        const float* __restrict__ dnW, const float* __restrict__ dnb,
        const float* __restrict__ outW, const float* __restrict__ outb,
        float* pred, int C) {
    __shared__ float sh[HD];
    int t = threadIdx.x;
    sh[t] = pooled[t] * invU;
    __syncthreads();
    float v = linb[t];
    for (int k = 0; k < HD; ++k) v += sh[k] * linW[k * HD + t];
    __syncthreads();
    sh[t] = v;
    __syncthreads();
    float d = dnb[t];
    for (int k = 0; k < HD; ++k) d += sh[k] * dnW[k * HD + t];
    d = fmaxf(d, 0.0f);
    __syncthreads();
    sh[t] = d;
    __syncthreads();
    if (t < C) {
        float p = outb[t];
        for (int k = 0; k < HD; ++k) p += sh[k] * outW[k * C + t];
        pred[t] = 1.0f / (1.0f + expf(-p));
    }
}

extern "C" void kernel_launch(void* const* d_in, const int* in_sizes, int n_in,
                              void* d_out, int out_size, void* d_ws, size_t ws_size,
                              hipStream_t stream) {
    const float* node_feat = (const float*)d_in[0];
    const float* edge_w    = (const float*)d_in[1];
    const float* h0        = (const float*)d_in[2];
    const float* Wz  = (const float*)d_in[3];  const float* bz  = (const float*)d_in[4];
    const float* Wr  = (const float*)d_in[5];  const float* br  = (const float*)d_in[6];
    const float* Wh  = (const float*)d_in[7];  const float* bh  = (const float*)d_in[8];
    const float* lzW = (const float*)d_in[9];  const float* lzb = (const float*)d_in[10];
    const float* lrW = (const float*)d_in[11]; const float* lrb = (const float*)d_in[12];
    const float* lhW = (const float*)d_in[13]; const float* lhb = (const float*)d_in[14];
    const float* linW= (const float*)d_in[15]; const float* linb= (const float*)d_in[16];
    const float* dnW = (const float*)d_in[17]; const float* dnb = (const float*)d_in[18];
    const float* outW= (const float*)d_in[19]; const float* outb= (const float*)d_in[20];
    const int* src  = (const int*)d_in[21];
    const int* dst  = (const int*)d_in[22];
    const int* nids = (const int*)d_in[23];

    const int N = in_sizes[2] / HD;
    const int E = in_sizes[1];
    const int U = in_sizes[23];
    const int C = in_sizes[20];
    const int NP = (N + 127) & ~127;    // row-padded
    const int NB1K = (N + 1023) / 1024; // scan blocks
    const int NR = (N + RSIZE - 1) / RSIZE;       // ranges
    const int NPAD = NR * RSIZE;
    int NEC = 64;                                  // edge chunks
    {   // keep per-chunk counts < 65536 for packed ushort ranks
        int minc = (E + 65535) / 65536;
        if (NEC < minc) NEC = minc;
    }
    const int EC = (E + NEC - 1) / NEC;

    float* out  = (float*)d_out;
    float* pred = out;          // [C]
    float* hout = out + C;      // [N,H]

    // workspace layout (16B-aligned chunks)
    char* p = (char*)d_ws;
    auto alloc = [&](size_t bytes) { char* r = p; p += (bytes + 15) & ~(size_t)15; return r; };
    float* dinv   = (float*)alloc((size_t)N * 4);
    float* pooled = (float*)alloc(HD * 4);
    int*   counts = (int*)alloc((size_t)N * 4);
    int*   row_ptr= (int*)alloc((size_t)(N + 1) * 4);
    int2*  es     = (int2*)alloc((size_t)E * 8);
    int*   bsums  = (int*)alloc((size_t)1024 * 4);
    int*   pc     = (int*)alloc((size_t)NEC * NPAD * 4);
    float* pw     = (float*)alloc((size_t)NEC * NPAD * 4);
    ushort* nfb   = (ushort*)alloc((size_t)NP * HD * 2);
    ushort* aggb  = (ushort*)alloc((size_t)NP * HD * 2);
    ushort* h0b   = (ushort*)alloc((size_t)NP * HD * 2);
    ushort* BT    = (ushort*)alloc((size_t)3 * 128 * 256 * 2);
    float* lb2    = (float*)alloc(384 * 4);

    hipMemsetAsync(pooled, 0, HD * sizeof(float), stream);

    int prep_items = N * (HD / 8);
    prep_kernel<<<(prep_items + 255) / 256, 256, 0, stream>>>(node_feat, h0, nfb, h0b, N);
    hist_lds_kernel<<<NR * NEC, 256, 0, stream>>>(dst, edge_w, pc, pw, NPAD, NR, EC, E);
    reduce_hist_kernel<<<(N + 255) / 256, 256, 0, stream>>>(pc, pw, counts, dinv,
                                                            NPAD, NEC, N);
    scan_partial_kernel<<<NB1K, 256, 0, stream>>>(counts, bsums, N);
    scan_bsums_kernel<<<1, 1024, 0, stream>>>(bsums, row_ptr + N, NB1K);
    scan_final_kernel<<<NB1K, 256, 0, stream>>>(counts, bsums, row_ptr, N);
    col_scan_kernel<<<(N + 255) / 256, 256, 0, stream>>>(row_ptr, pc, NPAD, NEC, N);
    fill2d_kernel<<<NEC * NR, 512, 0, stream>>>(src, dst, edge_w, dinv, pc,
                                                es, NPAD, NR, EC, E);
    dim3 fg(3, 16);
    fuse_weights_kernel<<<fg, 256, 0, stream>>>(Wz, Wr, Wh, lzW, lrW, lhW, BT);
    lb2_kernel<<<3, 128, 0, stream>>>(lzW, lrW, lhW, bz, br, bh, lzb, lrb, lhb, lb2);
    agg_feat_kernel<<<(N + 3) / 4, 256, 0, stream>>>(
        (const uint2*)nfb, dinv, row_ptr, es, (uint2*)aggb, N);
    gru_fused_kernel<<<NP / 64, 256, 0, stream>>>(aggb, h0b, BT, lb2, hout, N);
    pool_kernel<<<512, 128, 0, stream>>>(hout, nids, pooled, U);
    decoder_kernel<<<1, 128, 0, stream>>>(pooled, 1.0f / (float)U,
                                          linW, linb, dnW, dnb, outW, outb, pred, C);
}

// Round 16
// 259.996 us; speedup vs baseline: 1.0392x; 1.0073x over previous
//
#include <hip/hip_runtime.h>
#include <math.h>

// TGCN: bf16 feature-space GCN aggregation (fp32 accum) -> single fused GRU
// kernel (merged Z+R phase; hq overwrites Ah0 in-place -> 2 LDS buffers,
// 4 blocks/CU). CSR-by-dst with ZERO global atomics; int2 {src, w*dinv_s}.
// agg: uint2 gathers (2 edges per wave-instruction). pool: atomic-free partials.

#define HD 128
#define RBITS 13
#define RSIZE 8192          // nodes per histogram/fill range
#define POOLB 512           // pool partial blocks

typedef __attribute__((ext_vector_type(8))) short short8;
typedef __attribute__((ext_vector_type(4))) float f32x4;

__device__ __forceinline__ ushort f2bf(float f) {
    union { float f; unsigned u; } v; v.f = f;
    unsigned r = (v.u + 0x7FFFu + ((v.u >> 16) & 1u)) >> 16;
    return (ushort)r;
}
__device__ __forceinline__ float bf2f(ushort h) {
    union { unsigned u; float f; } v; v.u = ((unsigned)h) << 16;
    return v.f;
}
__device__ __forceinline__ float bflo(unsigned u) {
    union { unsigned u; float f; } v; v.u = u << 16; return v.f;
}
__device__ __forceinline__ float bfhi(unsigned u) {
    union { unsigned u; float f; } v; v.u = u & 0xFFFF0000u; return v.f;
}
__device__ __forceinline__ float fast_sigmoid(float x) {
    return 1.0f / (1.0f + __expf(-x));
}
__device__ __forceinline__ float fast_tanh(float x) {
    float e = __expf(-2.0f * fabsf(x));
    float m = (1.0f - e) / (1.0f + e);
    return copysignf(m, x);
}

// nf -> bf16, h0 -> bf16 (vectorized)
__global__ void prep_kernel(const float* __restrict__ nf, const float* __restrict__ h0,
                            ushort* __restrict__ nfb, ushort* __restrict__ h0b, int n) {
    int idx = blockIdx.x * 256 + threadIdx.x;
    int total8 = n * (HD / 8);
    if (idx < total8) {
        const float4* p = (const float4*)(nf + (size_t)idx * 8);
        float4 x = p[0], y = p[1];
        short8 o;
        o[0] = (short)f2bf(x.x); o[1] = (short)f2bf(x.y);
        o[2] = (short)f2bf(x.z); o[3] = (short)f2bf(x.w);
        o[4] = (short)f2bf(y.x); o[5] = (short)f2bf(y.y);
        o[6] = (short)f2bf(y.z); o[7] = (short)f2bf(y.w);
        *(short8*)(nfb + (size_t)idx * 8) = o;
        const float4* q = (const float4*)(h0 + (size_t)idx * 8);
        float4 a = q[0], b = q[1];
        short8 o2;
        o2[0] = (short)f2bf(a.x); o2[1] = (short)f2bf(a.y);
        o2[2] = (short)f2bf(a.z); o2[3] = (short)f2bf(a.w);
        o2[4] = (short)f2bf(b.x); o2[5] = (short)f2bf(b.y);
        o2[6] = (short)f2bf(b.z); o2[7] = (short)f2bf(b.w);
        *(short8*)(h0b + (size_t)idx * 8) = o2;
    }
}

// LDS-privatized histogram. Block (r = bid%NR, c = bid/NR).
__global__ __launch_bounds__(256) void hist_lds_kernel(
        const int* __restrict__ dst, const float* __restrict__ w,
        int* __restrict__ pc, float* __restrict__ pw,
        int NPAD, int NR, int EC, int E) {
    __shared__ int lc[RSIZE];
    __shared__ float lw[RSIZE];
    int r = blockIdx.x % NR;
    int c = blockIdx.x / NR;
    int t = threadIdx.x;
    for (int b = t; b < RSIZE; b += 256) { lc[b] = 0; lw[b] = 0.0f; }
    __syncthreads();
    int base = c * EC;
    int end = min(base + EC, E);
    int rbase = r << RBITS;
    for (int e = base + t; e < end; e += 256) {
        int d = dst[e];
        float wv = w[e];
        if ((d >> RBITS) == r) {
            atomicAdd(&lc[d - rbase], 1);
            atomicAdd(&lw[d - rbase], wv);
        }
    }
    __syncthreads();
    size_t o = (size_t)c * NPAD + rbase;
    for (int b = t; b < RSIZE; b += 256) {
        pc[o + b] = lc[b];
        pw[o + b] = lw[b];
    }
}

// counts[i] = sum_c pc[c][i];  dinv[i] = rsqrt(1 + sum_c pw[c][i])
__global__ __launch_bounds__(256) void reduce_hist_kernel(
        const int* __restrict__ pc, const float* __restrict__ pw,
        int* __restrict__ counts, float* __restrict__ dinv,
        int NPAD, int NEC, int N) {
    int i = blockIdx.x * 256 + threadIdx.x;
    if (i >= N) return;
    int ctot = 0;
    float d = 1.0f;   // self-loop
    for (int c = 0; c < NEC; ++c) {
        ctot += pc[(size_t)c * NPAD + i];
        d += pw[(size_t)c * NPAD + i];
    }
    counts[i] = ctot;
    dinv[i] = (d > 0.0f) ? rsqrtf(d) : 0.0f;
}

// ---- hierarchical scan ----
__global__ __launch_bounds__(256) void scan_partial_kernel(
        const int* __restrict__ counts, int* __restrict__ bsums, int n) {
    __shared__ int ws[4];
    int b = blockIdx.x, t = threadIdx.x;
    int idx = b * 1024 + t * 4;
    int4 v = {0, 0, 0, 0};
    if (idx + 3 < n) v = *(const int4*)(counts + idx);
    else {
        if (idx < n) v.x = counts[idx];
        if (idx + 1 < n) v.y = counts[idx + 1];
        if (idx + 2 < n) v.z = counts[idx + 2];
        if (idx + 3 < n) v.w = counts[idx + 3];
    }
    int s = v.x + v.y + v.z + v.w;
    for (int off = 1; off < 64; off <<= 1) s += __shfl_xor(s, off, 64);
    if ((t & 63) == 0) ws[t >> 6] = s;
    __syncthreads();
    if (t == 0) bsums[b] = ws[0] + ws[1] + ws[2] + ws[3];
}

__global__ __launch_bounds__(1024) void scan_bsums_kernel(
        int* __restrict__ bsums, int* __restrict__ rp_total, int nb) {
    __shared__ int ws[16];
    int t = threadIdx.x;
    int v = (t < nb) ? bsums[t] : 0;
    int lane = t & 63, wid = t >> 6;
    int x = v;
    for (int off = 1; off < 64; off <<= 1) {
        int y = __shfl_up(x, off, 64);
        if (lane >= off) x += y;
    }
    if (lane == 63) ws[wid] = x;
    __syncthreads();
    if (wid == 0) {
        int s = (lane < 16) ? ws[lane] : 0;
        for (int off = 1; off < 16; off <<= 1) {
            int y = __shfl_up(s, off, 64);
            if (lane >= off) s += y;
        }
        if (lane < 16) ws[lane] = s;
    }
    __syncthreads();
    int excl = x - v + ((wid == 0) ? 0 : ws[wid - 1]);
    if (t < nb) bsums[t] = excl;
    if (t == nb - 1) *rp_total = excl + v;
}

__global__ __launch_bounds__(256) void scan_final_kernel(
        const int* __restrict__ counts, const int* __restrict__ bsums,
        int* __restrict__ row_ptr, int n) {
    __shared__ int ws[4];
    int b = blockIdx.x, t = threadIdx.x;
    int idx = b * 1024 + t * 4;
    int4 v = {0, 0, 0, 0};
    if (idx + 3 < n) v = *(const int4*)(counts + idx);
    else {
        if (idx < n) v.x = counts[idx];
        if (idx + 1 < n) v.y = counts[idx + 1];
        if (idx + 2 < n) v.z = counts[idx + 2];
        if (idx + 3 < n) v.w = counts[idx + 3];
    }
    int s = v.x + v.y + v.z + v.w;
    int lane = t & 63, wid = t >> 6;
    int x = s;
    for (int off = 1; off < 64; off <<= 1) {
        int y = __shfl_up(x, off, 64);
        if (lane >= off) x += y;
    }
    if (lane == 63) ws[wid] = x;
    __syncthreads();
    int woff = 0;
    for (int wv = 0; wv < wid; ++wv) woff += ws[wv];
    int run = bsums[b] + woff + x - s;
    int4 rp;
    rp.x = run; rp.y = run + v.x; rp.z = rp.y + v.y; rp.w = rp.z + v.z;
    if (idx + 3 < n) {
        *(int4*)(row_ptr + idx) = rp;
    } else {
        if (idx < n) row_ptr[idx] = rp.x;
        if (idx + 1 < n) row_ptr[idx + 1] = rp.y;
        if (idx + 2 < n) row_ptr[idx + 2] = rp.z;
        if (idx + 3 < n) row_ptr[idx + 3] = rp.w;
    }
}

// pc[c][d] (counts) -> per-chunk CSR base offsets (in place)
__global__ __launch_bounds__(256) void col_scan_kernel(
        const int* __restrict__ row_ptr, int* __restrict__ pc,
        int NPAD, int NEC, int n) {
    int i = blockIdx.x * 256 + threadIdx.x;
    if (i >= n) return;
    int run = row_ptr[i];
    for (int c = 0; c < NEC; ++c) {
        size_t idx = (size_t)c * NPAD + i;
        int v = pc[idx];
        pc[idx] = run;
        run += v;
    }
}

// fill: block (c,r); pco range-slice preloaded into LDS; packed ushort ranks;
// ONE int2 {src, w*dinv_s} store per edge.
__global__ __launch_bounds__(512) void fill2d_kernel(
        const int* __restrict__ src, const int* __restrict__ dst,
        const float* __restrict__ w, const float* __restrict__ dinv,
        const int* __restrict__ pc, int2* __restrict__ es,
        int NPAD, int NR, int EC, int E) {
    __shared__ int po[RSIZE];            // 32KB preloaded base offsets
    __shared__ unsigned pk[RSIZE / 2];   // 16KB packed ushort cursors
    int r = blockIdx.x % NR;
    int c = blockIdx.x / NR;
    int t = threadIdx.x;
    const int* __restrict__ pco = pc + (size_t)c * NPAD + (r << RBITS);
    for (int b = t; b < RSIZE / 2; b += 512) pk[b] = 0u;
    for (int b = t; b < RSIZE; b += 512) po[b] = pco[b];
    __syncthreads();
    int base = c * EC;
    int end = min(base + EC, E);
    int rbase = r << RBITS;
    for (int e = base + t; e < end; e += 512) {
        int d = dst[e];
        if ((d >> RBITS) == r) {
            int dl = d - rbase;
            unsigned sh = (dl & 1) * 16;
            unsigned old = atomicAdd(&pk[dl >> 1], 1u << sh);
            int rank = (int)((old >> sh) & 0xFFFFu);
            int pos = po[dl] + rank;
            int s = src[e];
            float nv = dinv[s] * w[e];        // dinv[d] applied in agg epilogue
            int2 ev;
            ev.x = s;
            ev.y = __float_as_int(nv);
            es[pos] = ev;
        }
    }
}

// Fused-weight build, parallel+coalesced. grid (3,16), 256 thr.
__global__ __launch_bounds__(256) void fuse_weights_kernel(
        const float* __restrict__ Wz, const float* __restrict__ Wr,
        const float* __restrict__ Wh,
        const float* __restrict__ lzW, const float* __restrict__ lrW,
        const float* __restrict__ lhW,
        ushort* __restrict__ BT) {
    int g = blockIdx.x, kt = blockIdx.y;
    const float* W  = (g == 0) ? Wz  : (g == 1) ? Wr  : Wh;
    const float* lW = (g == 0) ? lzW : (g == 1) ? lrW : lhW;
    int t = threadIdx.x;
    int j = t & 127, kh = t >> 7;          // kh in {0,1}
    int k0 = kt * 8 + kh * 4;
    float m0 = 0.f, m1 = 0.f, m2 = 0.f, m3 = 0.f;
    for (int mm = 0; mm < 128; ++mm) {
        float lv = lW[mm * 128 + j];       // coalesced across j
        m0 += W[(k0 + 0) * 128 + mm] * lv; // wave-uniform -> broadcast
        m1 += W[(k0 + 1) * 128 + mm] * lv;
        m2 += W[(k0 + 2) * 128 + mm] * lv;
        m3 += W[(k0 + 3) * 128 + mm] * lv;
    }
    ushort* dstc = BT + ((size_t)g * 128 + j) * 256;
    dstc[k0 + 0] = f2bf(m0); dstc[k0 + 1] = f2bf(m1);
    dstc[k0 + 2] = f2bf(m2); dstc[k0 + 3] = f2bf(m3);
#pragma unroll
    for (int u = 0; u < 4; ++u) {
        int mm = k0 + u;
        dstc[128 + mm] = f2bf(lW[(128 + mm) * 128 + j]);
    }
}

// lb2[g][j] = lgb[j] + sum_m bg[m]*lgW_top[m][j]
__global__ __launch_bounds__(128) void lb2_kernel(
        const float* __restrict__ lzW, const float* __restrict__ lrW,
        const float* __restrict__ lhW,
        const float* __restrict__ bz, const float* __restrict__ br,
        const float* __restrict__ bh,
        const float* __restrict__ lzb, const float* __restrict__ lrb,
        const float* __restrict__ lhb,
        float* __restrict__ lb2) {
    int g = blockIdx.x, j = threadIdx.x;
    const float* lW = (g == 0) ? lzW : (g == 1) ? lrW : lhW;
    const float* bg = (g == 0) ? bz  : (g == 1) ? br  : bh;
    const float* lb = (g == 0) ? lzb : (g == 1) ? lrb : lhb;
    float s = lb[j];
    for (int mm = 0; mm < 128; ++mm) s += bg[mm] * lW[mm * 128 + j];
    lb2[g * 128 + j] = s;
}

// agg: ONE node per wave; half-waves take alternating 8-edge batches; uint2
// gathers. aggb[i,:] = bf16( dinv_i * (dinv_i*nf_i + sum_e (w*dinv_s)*nf_s) )
__global__ __launch_bounds__(256) void agg_feat_kernel(
        const uint2* __restrict__ nfb2, const float* __restrict__ dinv,
        const int* __restrict__ row_ptr, const int2* __restrict__ es,
        uint2* __restrict__ aggb2, int n) {
    int lane = threadIdx.x & 63;
    int wv = threadIdx.x >> 6;
    int i = blockIdx.x * 4 + wv;
    if (i >= n) return;
    int sub = lane & 31;
    int half = lane >> 5;
    float dA = dinv[i];
    float a0 = 0.f, a1 = 0.f, a2 = 0.f, a3 = 0.f;
    int e0 = row_ptr[i], e1 = row_ptr[i + 1];
    int iters = (e1 - e0 + 15) >> 4;

    int2 zed; zed.x = 0; zed.y = 0;
    int e = e0 + half * 8;
    int2 buf[8];
#pragma unroll
    for (int u = 0; u < 8; ++u) {
        int ee = e + u;
        buf[u] = (ee < e1) ? es[ee] : zed;
    }
    for (int it = 0; it < iters; ++it) {
        uint2 v[8]; float w[8];
#pragma unroll
        for (int u = 0; u < 8; ++u) {
            v[u] = nfb2[(size_t)buf[u].x * 32 + sub];
            w[u] = __int_as_float(buf[u].y);
        }
        int en = e + 16;
#pragma unroll
        for (int u = 0; u < 8; ++u) {
            int ee = en + u;
            buf[u] = (it + 1 < iters && ee < e1) ? es[ee] : zed;
        }
#pragma unroll
        for (int u = 0; u < 8; ++u) {
            a0 += w[u] * bflo(v[u].x);
            a1 += w[u] * bfhi(v[u].x);
            a2 += w[u] * bflo(v[u].y);
            a3 += w[u] * bfhi(v[u].y);
        }
        e = en;
    }
    a0 += __shfl_xor(a0, 32, 64);
    a1 += __shfl_xor(a1, 32, 64);
    a2 += __shfl_xor(a2, 32, 64);
    a3 += __shfl_xor(a3, 32, 64);
    if (half == 0) {
        uint2 self = nfb2[(size_t)i * 32 + sub];
        float f0 = dA * (dA * bflo(self.x) + a0);
        float f1 = dA * (dA * bfhi(self.x) + a1);
        float f2 = dA * (dA * bflo(self.y) + a2);
        float f3 = dA * (dA * bfhi(self.y) + a3);
        uint2 o;
        o.x = (unsigned)f2bf(f0) | ((unsigned)f2bf(f1) << 16);
        o.y = (unsigned)f2bf(f2) | ((unsigned)f2bf(f3) << 16);
        aggb2[(size_t)i * 32 + sub] = o;
    }
}

// Fused GRU, merged Z+R phase sharing A-reads; hq overwrites Ah0 in place
// (2 LDS buffers = 34.8KB -> 4 blocks/CU). h0 values needed by the final
// combine are saved per-thread in registers (hv).
#define BADDR(g, cf, ks) (BT + (size_t)((g) * 128 + c0 + (cf) * 16 + rlo) * 256 \
                          + (ks) * 32 + koff)
__global__ __launch_bounds__(256) void gru_fused_kernel(
        const ushort* __restrict__ aggb, const ushort* __restrict__ h0b,
        const ushort* __restrict__ BT, const float* __restrict__ lb2,
        float* __restrict__ hout, int n) {
    __shared__ ushort Aag[64][136];
    __shared__ ushort Ah0[64][136];   // h0; becomes hq after ZR phase
    int t = threadIdx.x;
    int i0 = blockIdx.x * 64;

    int w = t >> 6, lane = t & 63;
    int rlo = lane & 15, koff = (lane >> 4) * 8, rbase = (lane >> 4) * 4;
    int c0 = w * 32;

    short8 bz0 = *(const short8*)BADDR(0, 0, 0);
    short8 bz1 = *(const short8*)BADDR(0, 1, 0);
    short8 br0 = *(const short8*)BADDR(1, 0, 0);
    short8 br1 = *(const short8*)BADDR(1, 1, 0);

    for (int c = t; c < 1024; c += 256) {
        int row = c >> 4, c8 = c & 15;
        size_t gp = (size_t)(i0 + row) * HD + c8 * 8;
        *(short8*)&Aag[row][c8 * 8] = *(const short8*)(aggb + gp);
        *(short8*)&Ah0[row][c8 * 8] = *(const short8*)(h0b + gp);
    }
    __syncthreads();

    const f32x4 zero4 = {0.f, 0.f, 0.f, 0.f};
    f32x4 accz[4][2], accr[4][2];
#pragma unroll
    for (int rf = 0; rf < 4; ++rf) {
        accz[rf][0] = zero4; accz[rf][1] = zero4;
        accr[rf][0] = zero4; accr[rf][1] = zero4;
    }

    // ===== merged ZR phase =====
#pragma unroll
    for (int ks = 0; ks < 8; ++ks) {
        short8 nz0, nz1, nr0, nr1;
        if (ks < 7) {
            nz0 = *(const short8*)BADDR(0, 0, ks + 1);
            nz1 = *(const short8*)BADDR(0, 1, ks + 1);
            nr0 = *(const short8*)BADDR(1, 0, ks + 1);
            nr1 = *(const short8*)BADDR(1, 1, ks + 1);
        }
#pragma unroll
        for (int rf = 0; rf < 4; ++rf) {
            short8 af = (ks < 4)
                ? *(const short8*)&Aag[rf * 16 + rlo][ks * 32 + koff]
                : *(const short8*)&Ah0[rf * 16 + rlo][(ks - 4) * 32 + koff];
            accz[rf][0] = __builtin_amdgcn_mfma_f32_16x16x32_bf16(af, bz0, accz[rf][0], 0, 0, 0);
            accz[rf][1] = __builtin_amdgcn_mfma_f32_16x16x32_bf16(af, bz1, accz[rf][1], 0, 0, 0);
            accr[rf][0] = __builtin_amdgcn_mfma_f32_16x16x32_bf16(af, br0, accr[rf][0], 0, 0, 0);
            accr[rf][1] = __builtin_amdgcn_mfma_f32_16x16x32_bf16(af, br1, accr[rf][1], 0, 0, 0);
        }
        if (ks < 7) { bz0 = nz0; bz1 = nz1; br0 = nr0; br1 = nr1; }
    }

    // epilogue part A (register-only + reads): z, save h0
    float zv[4][2][4], hv[4][2][4];
#pragma unroll
    for (int rf = 0; rf < 4; ++rf)
#pragma unroll
        for (int cf = 0; cf < 2; ++cf) {
            int lc = c0 + cf * 16 + rlo;
            float bvz = lb2[lc];
#pragma unroll
            for (int i = 0; i < 4; ++i) {
                int row = rf * 16 + rbase + i;
                zv[rf][cf][i] = fast_sigmoid(accz[rf][cf][i] + bvz);
                hv[rf][cf][i] = bf2f(Ah0[row][lc]);
            }
        }
    __syncthreads();   // all ZR reads of Ah0 complete

    // part B: hq = sigmoid(r) * h0 -> overwrite Ah0
#pragma unroll
    for (int rf = 0; rf < 4; ++rf)
#pragma unroll
        for (int cf = 0; cf < 2; ++cf) {
            int lc = c0 + cf * 16 + rlo;
            float bvr = lb2[128 + lc];
#pragma unroll
            for (int i = 0; i < 4; ++i) {
                int row = rf * 16 + rbase + i;
                float r = fast_sigmoid(accr[rf][cf][i] + bvr);
                Ah0[row][lc] = f2bf(r * hv[rf][cf][i]);
            }
        }
    short8 bh0 = *(const short8*)BADDR(2, 0, 0);
    short8 bh1 = *(const short8*)BADDR(2, 1, 0);
    __syncthreads();   // hq visible to all waves

    // ===== HT phase: A = [Aag | hq] =====
    f32x4 acch[4][2];
#pragma unroll
    for (int rf = 0; rf < 4; ++rf) { acch[rf][0] = zero4; acch[rf][1] = zero4; }
#pragma unroll
    for (int ks = 0; ks < 8; ++ks) {
        short8 nh0, nh1;
        if (ks < 7) {
            nh0 = *(const short8*)BADDR(2, 0, ks + 1);
            nh1 = *(const short8*)BADDR(2, 1, ks + 1);
        }
#pragma unroll
        for (int rf = 0; rf < 4; ++rf) {
            short8 af = (ks < 4)
                ? *(const short8*)&Aag[rf * 16 + rlo][ks * 32 + koff]
                : *(const short8*)&Ah0[rf * 16 + rlo][(ks - 4) * 32 + koff];
            acch[rf][0] = __builtin_amdgcn_mfma_f32_16x16x32_bf16(af, bh0, acch[rf][0], 0, 0, 0);
            acch[rf][1] = __builtin_amdgcn_mfma_f32_16x16x32_bf16(af, bh1, acch[rf][1], 0, 0, 0);
        }
        if (ks < 7) { bh0 = nh0; bh1 = nh1; }
    }
#pragma unroll
    for (int rf = 0; rf < 4; ++rf)
#pragma unroll
        for (int cf = 0; cf < 2; ++cf) {
            int lc = c0 + cf * 16 + rlo;
            float bv = lb2[256 + lc];
#pragma unroll
            for (int i = 0; i < 4; ++i) {
                int row = rf * 16 + rbase + i;
                int grow = i0 + row;
                if (grow < n) {
                    float ht = fast_tanh(acch[rf][cf][i] + bv);
                    float z = zv[rf][cf][i];
                    hout[(size_t)grow * HD + lc] = z * hv[rf][cf][i] + (1.0f - z) * ht;
                }
            }
        }
}

// pool: per-block partials, NO atomics (atomic ping-pong on 2 lines was the
// R8-style disease). partials[b][128] reduced in decoder.
__global__ __launch_bounds__(128) void pool_partial_kernel(
        const float* __restrict__ hout, const int* __restrict__ nids,
        float* __restrict__ partials, int U) {
    int t = threadIdx.x;
    float pa = 0.0f;
    for (int u = blockIdx.x; u < U; u += gridDim.x) {
        int nid = nids[u];
        pa += fmaxf(hout[(size_t)nid * HD + t], 0.0f);
    }
    partials[(size_t)blockIdx.x * HD + t] = pa;
}

__global__ __launch_bounds__(128) void decoder_kernel(
        const float* __restrict__ partials, float invU,
        const float* __restrict__ linW, const float* __restrict__ linb,
        const float* __restrict__ dnW, const float* __restrict__ dnb,
        const float* __restrict__ outW, const float* __restrict__ outb,
        float* pred, int C) {
    __shared__ float sh[HD];
    int t = threadIdx.x;
    float s = 0.0f;
    for (int b = 0; b < POOLB; ++b) s += partials[(size_t)b * HD + t];
    sh[t] = s * invU;
    __syncthreads();
    float v = linb[t];
    for (int k = 0; k < HD; ++k) v += sh[k] * linW[k * HD + t];
    __syncthreads();
    sh[t] = v;
    __syncthreads();
    float d = dnb[t];
    for (int k = 0; k < HD; ++k) d += sh[k] * dnW[k * HD + t];
    d = fmaxf(d, 0.0f);
    __syncthreads();
    sh[t] = d;
    __syncthreads();
    if (t < C) {
        float p = outb[t];
        for (int k = 0; k < HD; ++k) p += sh[k] * outW[k * C + t];
        pred[t] = 1.0f / (1.0f + expf(-p));
    }
}

extern "C" void kernel_launch(void* const* d_in, const int* in_sizes, int n_in,
                              void* d_out, int out_size, void* d_ws, size_t ws_size,
                              hipStream_t stream) {
    const float* node_feat = (const float*)d_in[0];
    const float* edge_w    = (const float*)d_in[1];
    const float* h0        = (const float*)d_in[2];
    const float* Wz  = (const float*)d_in[3];  const float* bz  = (const float*)d_in[4];
    const float* Wr  = (const float*)d_in[5];  const float* br  = (const float*)d_in[6];
    const float* Wh  = (const float*)d_in[7];  const float* bh  = (const float*)d_in[8];
    const float* lzW = (const float*)d_in[9];  const float* lzb = (const float*)d_in[10];
    const float* lrW = (const float*)d_in[11]; const float* lrb = (const float*)d_in[12];
    const float* lhW = (const float*)d_in[13]; const float* lhb = (const float*)d_in[14];
    const float* linW= (const float*)d_in[15]; const float* linb= (const float*)d_in[16];
    const float* dnW = (const float*)d_in[17]; const float* dnb = (const float*)d_in[18];
    const float* outW= (const float*)d_in[19]; const float* outb= (const float*)d_in[20];
    const int* src  = (const int*)d_in[21];
    const int* dst  = (const int*)d_in[22];
    const int* nids = (const int*)d_in[23];

    const int N = in_sizes[2] / HD;
    const int E = in_sizes[1];
    const int U = in_sizes[23];
    const int C = in_sizes[20];
    const int NP = (N + 127) & ~127;    // row-padded
    const int NB1K = (N + 1023) / 1024; // scan blocks
    const int NR = (N + RSIZE - 1) / RSIZE;       // ranges
    const int NPAD = NR * RSIZE;
    int NEC = 64;                                  // edge chunks
    {   // keep per-chunk counts < 65536 for packed ushort ranks
        int minc = (E + 65535) / 65536;
        if (NEC < minc) NEC = minc;
    }
    const int EC = (E + NEC - 1) / NEC;

    float* out  = (float*)d_out;
    float* pred = out;          // [C]
    float* hout = out + C;      // [N,H]

    // workspace layout (16B-aligned chunks)
    char* p = (char*)d_ws;
    auto alloc = [&](size_t bytes) { char* r = p; p += (bytes + 15) & ~(size_t)15; return r; };
    float* dinv   = (float*)alloc((size_t)N * 4);
    float* partials = (float*)alloc((size_t)POOLB * HD * 4);
    int*   counts = (int*)alloc((size_t)N * 4);
    int*   row_ptr= (int*)alloc((size_t)(N + 1) * 4);
    int2*  es     = (int2*)alloc((size_t)E * 8);
    int*   bsums  = (int*)alloc((size_t)1024 * 4);
    int*   pc     = (int*)alloc((size_t)NEC * NPAD * 4);
    float* pw     = (float*)alloc((size_t)NEC * NPAD * 4);
    ushort* nfb   = (ushort*)alloc((size_t)NP * HD * 2);
    ushort* aggb  = (ushort*)alloc((size_t)NP * HD * 2);
    ushort* h0b   = (ushort*)alloc((size_t)NP * HD * 2);
    ushort* BT    = (ushort*)alloc((size_t)3 * 128 * 256 * 2);
    float* lb2    = (float*)alloc(384 * 4);

    int prep_items = N * (HD / 8);
    prep_kernel<<<(prep_items + 255) / 256, 256, 0, stream>>>(node_feat, h0, nfb, h0b, N);
    hist_lds_kernel<<<NR * NEC, 256, 0, stream>>>(dst, edge_w, pc, pw, NPAD, NR, EC, E);
    reduce_hist_kernel<<<(N + 255) / 256, 256, 0, stream>>>(pc, pw, counts, dinv,
                                                            NPAD, NEC, N);
    scan_partial_kernel<<<NB1K, 256, 0, stream>>>(counts, bsums, N);
    scan_bsums_kernel<<<1, 1024, 0, stream>>>(bsums, row_ptr + N, NB1K);
    scan_final_kernel<<<NB1K, 256, 0, stream>>>(counts, bsums, row_ptr, N);
    col_scan_kernel<<<(N + 255) / 256, 256, 0, stream>>>(row_ptr, pc, NPAD, NEC, N);
    fill2d_kernel<<<NEC * NR, 512, 0, stream>>>(src, dst, edge_w, dinv, pc,
                                                es, NPAD, NR, EC, E);
    dim3 fg(3, 16);
    fuse_weights_kernel<<<fg, 256, 0, stream>>>(Wz, Wr, Wh, lzW, lrW, lhW, BT);
    lb2_kernel<<<3, 128, 0, stream>>>(lzW, lrW, lhW, bz, br, bh, lzb, lrb, lhb, lb2);
    agg_feat_kernel<<<(N + 3) / 4, 256, 0, stream>>>(
        (const uint2*)nfb, dinv, row_ptr, es, (uint2*)aggb, N);
    gru_fused_kernel<<<NP / 64, 256, 0, stream>>>(aggb, h0b, BT, lb2, hout, N);
    pool_partial_kernel<<<POOLB, 128, 0, stream>>>(hout, nids, partials, U);
    decoder_kernel<<<1, 128, 0, stream>>>(partials, 1.0f / (float)U,
                                          linW, linb, dnW, dnb, outW, outb, pred, C);
}